// Round 4
// baseline (415.950 us; speedup 1.0000x reference)
//
#include <hip/hip_runtime.h>

// Problem constants (fixed by setup_inputs)
#define BATCH    4
#define NQ       10000
#define EMB      256
#define NH       8
#define DH       32
#define NL       4
#define NP       8
#define S_TOTAL  19560
#define NROW     (BATCH * NQ)          // 40000
#define VROWS    (BATCH * S_TOTAL)     // 78240

typedef _Float16 half8 __attribute__((ext_vector_type(8)));
typedef _Float16 half4v __attribute__((ext_vector_type(4)));
typedef _Float16 half2v __attribute__((ext_vector_type(2)));
typedef float floatx4 __attribute__((ext_vector_type(4)));

#define GLOBAL_AS __attribute__((address_space(1)))
#define LDS_AS    __attribute__((address_space(3)))

// ---------------------------------------------------------------------------
// One-shot weight prep: transpose+swizzle all three weight matrices to f16.
// Logical row n (0..1023): [0,512) w_off -> wT768, [512,768) w_attn -> wT768,
// [768,1024) w_val (256 rows) -> wvaT. Swizzle: 16B chunk c of row n lands at
// chunk c ^ (n&7).
// ---------------------------------------------------------------------------
__global__ __launch_bounds__(256) void prep_weights(
    const float* __restrict__ w_off, const float* __restrict__ w_attn,
    const float* __restrict__ w_val, _Float16* __restrict__ wT768,
    _Float16* __restrict__ wvaT) {
  const int tid = blockIdx.x * 256 + threadIdx.x;   // over 1024*256
  const int n = tid >> 8, k = tid & 255;
  const int c = k >> 3, e = k & 7;
  const int swz = ((c ^ (n & 7)) << 3) + e;
  float v;
  _Float16* dst;
  if (n < 512)      { v = w_off[(size_t)k * 512 + n];          dst = wT768 + (size_t)n * 256; }
  else if (n < 768) { v = w_attn[(size_t)k * 256 + (n - 512)]; dst = wT768 + (size_t)n * 256; }
  else              { v = w_val[(size_t)k * 256 + (n - 768)];  dst = wvaT + (size_t)(n - 768) * 256; }
  dst[swz] = (_Float16)v;
}

// ---------------------------------------------------------------------------
// MFMA GEMM: A-register-resident + B-chunk-in-LDS, 3 blocks/CU.
//   C = A[M,256]_f32 @ WTs[NC,256]^T + bias(col-select)
// Register-prefetch double-buffer; SWZ path uses swapped-operand MFMA so the
// 4 acc regs land on 4 consecutive channels -> coalesced 8B half4 stores.
// (r3 verified correct; GEMM time is NOT the bottleneck — left as-is.)
// ---------------------------------------------------------------------------
template <int NC, int NYS, bool SWZ>
__global__ __launch_bounds__(256, 3) void gemm6(
    const float* __restrict__ A, const _Float16* __restrict__ WTs,
    const float* __restrict__ bias0, const float* __restrict__ bias1,
    int splitc, _Float16* __restrict__ C, int M) {
  __shared__ _Float16 bsm[64 * 256];   // 32 KB B chunk (swizzled rows)
  const int t = threadIdx.x;
  const int wave = t >> 6, lane = t & 63;
  const int l15 = lane & 15, quad = lane >> 4;
  const int m0 = blockIdx.x * 128 + wave * 32;
  const int nlo = blockIdx.y * (NC / NYS);
  const int nchunks = (NC / NYS) / 64;

  const _Float16* src = WTs + (size_t)nlo * 256;

  // ---- issue chunk-0 B loads first (latency covered by A load+convert) ----
  half8 pb[8];
  #pragma unroll
  for (int i = 0; i < 8; ++i)
    pb[i] = *(const half8*)(src + t * 8 + i * 2048);

  // ---- load + convert the wave's A slice (32 rows x 256) ----
  half8 a[2][8];
  #pragma unroll
  for (int i = 0; i < 2; ++i) {
    const float* Ar = A + (size_t)min(m0 + 16 * i + l15, M - 1) * 256 + quad * 8;
    #pragma unroll
    for (int ks = 0; ks < 8; ++ks) {
      const float4 f0 = *(const float4*)(Ar + ks * 32);
      const float4 f1 = *(const float4*)(Ar + ks * 32 + 4);
      a[i][ks][0] = (_Float16)f0.x; a[i][ks][1] = (_Float16)f0.y;
      a[i][ks][2] = (_Float16)f0.z; a[i][ks][3] = (_Float16)f0.w;
      a[i][ks][4] = (_Float16)f1.x; a[i][ks][5] = (_Float16)f1.y;
      a[i][ks][6] = (_Float16)f1.z; a[i][ks][7] = (_Float16)f1.w;
    }
  }

  #pragma unroll
  for (int i = 0; i < 8; ++i)
    *(half8*)&bsm[t * 8 + i * 2048] = pb[i];
  __syncthreads();

  for (int ch = 0; ch < nchunks; ++ch) {
    // prefetch next chunk into registers (overlaps with compute below)
    if (ch + 1 < nchunks) {
      const _Float16* s2 = src + (size_t)(ch + 1) * 64 * 256;
      #pragma unroll
      for (int i = 0; i < 8; ++i)
        pb[i] = *(const half8*)(s2 + t * 8 + i * 2048);
    }

    floatx4 acc[2][4] = {};
    #pragma unroll
    for (int ks = 0; ks < 8; ++ks) {
      half8 b[4];
      #pragma unroll
      for (int j = 0; j < 4; ++j)
        b[j] = *(const half8*)&bsm[(16 * j + l15) * 256 +
                                   ((((ks * 4 + quad) ^ (l15 & 7))) << 3)];
      if constexpr (SWZ) {
        #pragma unroll
        for (int j = 0; j < 4; ++j)
          #pragma unroll
          for (int i = 0; i < 2; ++i)
            acc[i][j] = __builtin_amdgcn_mfma_f32_16x16x32_f16(b[j], a[i][ks], acc[i][j], 0, 0, 0);
      } else {
        #pragma unroll
        for (int j = 0; j < 4; ++j)
          #pragma unroll
          for (int i = 0; i < 2; ++i)
            acc[i][j] = __builtin_amdgcn_mfma_f32_16x16x32_f16(a[i][ks], b[j], acc[i][j], 0, 0, 0);
      }
    }

    const int nc0 = nlo + ch * 64;

    if constexpr (SWZ) {
      #pragma unroll
      for (int j = 0; j < 4; ++j) {
        const int col0 = nc0 + 16 * j + quad * 4;
        const int h = col0 >> 5, c0 = col0 & 31;
        const float4 bq = *(const float4*)(bias0 + col0);
        #pragma unroll
        for (int i = 0; i < 2; ++i) {
          const int row = m0 + 16 * i + l15;
          if (row < M) {
            const int b = row / S_TOTAL;
            const int s = row - b * S_TOTAL;
            half4v pk;
            pk[0] = (_Float16)(acc[i][j][0] + bq.x);
            pk[1] = (_Float16)(acc[i][j][1] + bq.y);
            pk[2] = (_Float16)(acc[i][j][2] + bq.z);
            pk[3] = (_Float16)(acc[i][j][3] + bq.w);
            *(half4v*)(C + ((((size_t)b * NH + h) * S_TOTAL + s) * 32 + c0)) = pk;
          }
        }
      }
    } else {
      float bc[4];
      #pragma unroll
      for (int j = 0; j < 4; ++j) {
        const int col = nc0 + 16 * j + l15;
        bc[j] = (col < splitc) ? bias0[col] : bias1[col - splitc];
      }
      #pragma unroll
      for (int i = 0; i < 2; ++i) {
        #pragma unroll
        for (int r = 0; r < 4; ++r) {
          const int row = m0 + 16 * i + quad * 4 + r;
          if (row < M) {
            #pragma unroll
            for (int j = 0; j < 4; ++j)
              C[(size_t)row * NC + nc0 + 16 * j + l15] =
                  (_Float16)(acc[i][j][r] + bc[j]);
          }
        }
      }
    }

    __syncthreads();               // all waves done reading bsm
    if (ch + 1 < nchunks) {
      #pragma unroll
      for (int i = 0; i < 8; ++i)
        *(half8*)&bsm[t * 8 + i * 2048] = pb[i];
      __syncthreads();
    }
  }
}

// ---------------------------------------------------------------------------
// Fused softmax + deformable bilinear sampling. vproj [B,H,S,32].
//
// Round-12: async-DMA gather staging via global_load_lds.
//   Evidence r8-r10: compiler NEVER keeps >8 gather results in VGPRs
//   (VGPR 40/32/44 across 3 source structures) -> ~8 loads in flight/wave
//   -> latency-serialized (~104us of the 195.8). global_load_lds takes a
//   PER-LANE global address, writes LDS at uniform base + lane*16, counts
//   on vmcnt, uses NO result VGPRs -> MLP decoupled from regalloc.
// Structure: per wave (2 heads), 4 batches (batch r == level r). Per batch:
//   4x global_load_lds (64 lanes x 16B = 8 row-pair fetches of 128B; pixels
//   xb,xb+1 are contiguous so one 128B fetch covers both bilinear x-taps),
//   s_waitcnt vmcnt(0), then ds_read_b64 + FMA (consumption unchanged).
// LDS: stage 16KB + addr 2KB + w 4KB = 22.5KB -> 7 blocks/CU = 28 waves/CU
// (up from ~20), each with 4 async gathers in flight.
// ---------------------------------------------------------------------------
__global__ __launch_bounds__(256, 4) void msda_sample(
    const _Float16* __restrict__ vproj,     // [B,H,S,32] f16 (+guards)
    const _Float16* __restrict__ fused,     // [B*Q, 768] f16: off(512)|logit(256)
    const float* __restrict__ ref,          // [B*Q, 4, 2] f32
    float* __restrict__ out) {              // [B*Q, 256] f32
  const int lvl_h[NL] = {92, 46, 23, 12};
  const int lvl_w[NL] = {160, 80, 40, 20};
  const int lvl_s[NL] = {0, 14720, 18400, 19320};

  __shared__ int      addr_s[512];    // [(h*32+lp)*2 + row]
  __shared__ float    w2_s[1024];     // [side*512 + (h*32+lp)*2 + row]
  __shared__ _Float16 stage[4][2048]; // per-wave 4KB batch buffer

  const int t   = threadIdx.x;
  const int blk = blockIdx.x;
  const int b   = blk & 3;             // pins batch to XCD (blk%8 round-robin)
  const int q   = blk >> 2;
  const int row = b * NQ + q;

  const int h  = t >> 5;
  const int lp = t & 31;
  const int l  = lp >> 3;
  const int p  = lp & 7;

  // ---- softmax over the 32 (l,p) logits of this head (xor shuffles) ----
  const float logit = (float)fused[(size_t)row * 768 + 512 + t];
  float mxv = logit;
  #pragma unroll
  for (int m = 1; m < 32; m <<= 1) mxv = fmaxf(mxv, __shfl_xor(mxv, m));
  const float e = __expf(logit - mxv);
  float sum = e;
  #pragma unroll
  for (int m = 1; m < 32; m <<= 1) sum += __shfl_xor(sum, m);
  const float attnw = e / sum;

  // ---- location & bilinear setup ----
  const half2v o2 = *(const half2v*)(fused + (size_t)row * 768 + 2 * t);
  const float ox = (float)o2[0], oy = (float)o2[1];
  const int z = p & 3;                       // NP=8 split (2,4): z = p % 4
  const float rx = ref[((size_t)row * 4 + z) * 2 + 0];
  const float ry = ref[((size_t)row * 4 + z) * 2 + 1];
  const int Wl = lvl_w[l], Hl = lvl_h[l], st = lvl_s[l];

  const float px = fmaf(rx, (float)Wl, ox) - 0.5f;
  const float py = fmaf(ry, (float)Hl, oy) - 0.5f;
  const float x0f = floorf(px), y0f = floorf(py);
  const float wx = px - x0f, wy = py - y0f;
  const int x0 = (int)x0f, y0 = (int)y0f;
  const int x1 = x0 + 1,   y1 = y0 + 1;

  // x: one 128B segment based at xb covers slots xb (left) and xb+1 (right)
  const float mx0 = (x0 >= 0 && x0 < Wl) ? 1.f : 0.f;
  const float mx1 = (x1 >= 0 && x1 < Wl) ? 1.f : 0.f;
  const float my0 = (y0 >= 0 && y0 < Hl) ? 1.f : 0.f;
  const float my1 = (y1 >= 0 && y1 < Hl) ? 1.f : 0.f;
  const int xb  = min(max(x0, -1), Wl - 1);          // guard pages cover x=-1/W
  const int cy0 = min(max(y0, 0), Hl - 1);
  const int cy1 = min(max(y1, 0), Hl - 1);

  const int bh   = b * NH + h;
  const int lbase = bh * S_TOTAL + st;
  const float wlc = attnw * (1.f - wx) * mx0;
  const float wrc = attnw * wx * mx1;

  addr_s[2 * t + 0] = (lbase + cy0 * Wl + xb) * 32;
  addr_s[2 * t + 1] = (lbase + cy1 * Wl + xb) * 32;
  w2_s[2 * t + 0]       = wlc * (1.f - wy) * my0;   // left,  top row
  w2_s[2 * t + 1]       = wlc * wy * my1;           // left,  bottom row
  w2_s[512 + 2 * t + 0] = wrc * (1.f - wy) * my0;   // right, top row
  w2_s[512 + 2 * t + 1] = wrc * wy * my1;           // right, bottom row
  __syncthreads();

  // ---- phase 2 ----
  const int wv = t >> 6;          // wave 0..3 (owns heads 2wv, 2wv+1)
  const int ln = t & 63;
  const int sub8 = ln >> 3;       // row-fetch sub-index within an inst
  const int chk  = ln & 7;        // 16B chunk within the 128B row-fetch
  const int g  = t & 31;
  const int c  = g & 7;           // channel quad: channels 4c..4c+3
  const int sd = (g >> 3) & 1;    // 0 = left pixel (xb), 1 = right (xb+1)
  const int ph = g >> 4;          // point parity
  const int wbase = sd << 9;
  const int h1 = h & 1;           // head within wave

  float a0 = 0.f, a1 = 0.f, a2 = 0.f, a3 = 0.f;

  #pragma unroll
  for (int r = 0; r < 4; ++r) {   // batch r == level r
    // make sure last batch's ds_reads have retired before DMA overwrites
    asm volatile("s_waitcnt lgkmcnt(0)" ::: "memory");

    // issue 4 async gathers: inst j covers row-fetches rf = j*8 + sub8,
    // rf in [0,32): h2 = rf>>4, ii = (rf>>2)&3, php = (rf>>1)&1, rw = rf&1.
    // Each row-fetch = 128B (both pixels, 32ch x 2 sides) of one y-row.
    #pragma unroll
    for (int j = 0; j < 4; ++j) {
      const int rf  = j * 8 + sub8;
      const int h2  = rf >> 4;
      const int ii  = (rf >> 2) & 3;
      const int php = (rf >> 1) & 1;
      const int rw  = rf & 1;
      const int lpx = 8 * r + 2 * ii + php;
      const int aidx = (((wv * 2 + h2) << 5) + lpx) * 2 + rw;
      const char* gp = (const char*)vproj + (ptrdiff_t)addr_s[aidx] * 2 + chk * 16;
      __builtin_amdgcn_global_load_lds(
          (const GLOBAL_AS void*)gp,
          (LDS_AS void*)&stage[wv][j * 512], 16, 0, 0);
    }
    asm volatile("s_waitcnt vmcnt(0)" ::: "memory");

    // consume: 4 points-pairs of this level; data is wave-private in LDS
    #pragma unroll
    for (int ii = 0; ii < 4; ++ii) {
      const int lpx = 8 * r + 2 * ii + ph;
      const int idx = ((h << 5) + lpx) << 1;
      const float2 wp = *(const float2*)&w2_s[wbase + idx];   // (top, bottom)
      const int rft = (h1 << 4) + (ii << 2) + (ph << 1);       // row 0
      const half4v vt = *(const half4v*)&stage[wv][rft * 64 + sd * 32 + 4 * c];
      const half4v vb = *(const half4v*)&stage[wv][(rft + 1) * 64 + sd * 32 + 4 * c];
      a0 = fmaf(wp.x, (float)vt[0], a0); a1 = fmaf(wp.x, (float)vt[1], a1);
      a2 = fmaf(wp.x, (float)vt[2], a2); a3 = fmaf(wp.x, (float)vt[3], a3);
      a0 = fmaf(wp.y, (float)vb[0], a0); a1 = fmaf(wp.y, (float)vb[1], a1);
      a2 = fmaf(wp.y, (float)vb[2], a2); a3 = fmaf(wp.y, (float)vb[3], a3);
    }
  }

  // reduce over side (xor 8) and point parity (xor 16)
  a0 += __shfl_xor(a0, 8);  a1 += __shfl_xor(a1, 8);
  a2 += __shfl_xor(a2, 8);  a3 += __shfl_xor(a3, 8);
  a0 += __shfl_xor(a0, 16); a1 += __shfl_xor(a1, 16);
  a2 += __shfl_xor(a2, 16); a3 += __shfl_xor(a3, 16);

  if (g < 8) {    // sd==0 && ph==0: 8 lanes own the 8 channel quads
    float4 o; o.x = a0; o.y = a1; o.z = a2; o.w = a3;
    *(float4*)(out + (size_t)row * 256 + (h << 5) + 4 * c) = o;
  }
}

extern "C" void kernel_launch(void* const* d_in, const int* in_sizes, int n_in,
                              void* d_out, int out_size, void* d_ws, size_t ws_size,
                              hipStream_t stream) {
  const float* query  = (const float*)d_in[0];  // [4,10000,256]
  const float* value  = (const float*)d_in[1];  // [4,19560,256]
  const float* refpts = (const float*)d_in[2];  // [4,10000,4,2]
  const float* w_off  = (const float*)d_in[3];  // [256,512]
  const float* b_off  = (const float*)d_in[4];  // [512]
  const float* w_attn = (const float*)d_in[5];  // [256,256]
  const float* b_attn = (const float*)d_in[6];  // [256]
  const float* w_val  = (const float*)d_in[7];  // [256,256]
  const float* b_val  = (const float*)d_in[8];  // [256]
  float* out = (float*)d_out;

  // workspace layout (16B-multiple segments; 256B guards around vh for the
  // x=-1 / x=W edge reads, whose weights are zero)
  char* p = (char*)d_ws;
  p += 256;                                                         // front guard
  _Float16* vh    = (_Float16*)p;  p += (size_t)VROWS * 256 * 2;    // 40.1 MB
  p += 256;                                                         // back guard
  _Float16* wT768 = (_Float16*)p;  p += (size_t)768 * 256 * 2;      // swizzled
  _Float16* wvaT  = (_Float16*)p;  p += (size_t)256 * 256 * 2;      // swizzled
  _Float16* fused_h = (_Float16*)p; p += (size_t)NROW * 768 * 2;    // 61.4 MB

  // prep: all weight transposes in one launch
  prep_weights<<<1024, 256, 0, stream>>>(w_off, w_attn, w_val, wT768, wvaT);

  // GEMMs: A register-resident, B chunks via LDS, register-prefetch dbuf.
  // v = value@w_val -> [B,H,S,32] swizzled (coalesced half4 stores);
  // fused = query@[w_off|w_attn]
  gemm6<256, 1, true><<<dim3((VROWS + 127) / 128, 1), 256, 0, stream>>>(
      value, wvaT, b_val, b_val, 1 << 30, vh, VROWS);
  gemm6<768, 2, false><<<dim3((NROW + 127) / 128, 2), 256, 0, stream>>>(
      query, wT768, b_off, b_attn, 512, fused_h, NROW);

  // softmax + sample + weighted sum
  msda_sample<<<dim3(NROW), 256, 0, stream>>>(vh, fused_h, refpts, out);
}